// Round 7
// baseline (460.437 us; speedup 1.0000x reference)
//
#include <hip/hip_runtime.h>

#define KITER 10
#define TILE 4096
#define BCAP 16384  // bucket staging capacity (expected 8192/bucket, +90 sigma)
typedef unsigned short bf16_t;
typedef __attribute__((ext_vector_type(4))) short bf16x4;
typedef __attribute__((ext_vector_type(8))) short bf16x8;
typedef __attribute__((ext_vector_type(4))) float f32x4;

__device__ __forceinline__ float bf2f(bf16_t u) {
  union { unsigned u; float f; } cv;
  cv.u = ((unsigned)u) << 16;
  return cv.f;
}
__device__ __forceinline__ bf16_t f2bf(float f) {
  unsigned u = __float_as_uint(f);
  unsigned r = (u + 0x7FFFu + ((u >> 16) & 1u)) >> 16;  // round-nearest-even
  return (bf16_t)r;
}

// ---------------- bucket cursor init: bcur[b] = b*BCAP ----------------
__global__ void k_initb(int* __restrict__ bcur, int nbuck) {
  int i = threadIdx.x;
  if (i < nbuck) bcur[i] = i * BCAP;
}

// ---------------- bucket sort pass A: tile -> per-bucket coalesced runs ------
__global__ __launch_bounds__(256) void k_bucket(const int* __restrict__ ei, int E,
                                                int* __restrict__ bcur,
                                                int2* __restrict__ barr) {
  __shared__ int hist[256];
  __shared__ int scn[256];
  __shared__ int excl[256];
  __shared__ int gb[256];
  __shared__ unsigned char lb[TILE];
  __shared__ int2 stg[TILE];
  int t = threadIdx.x;
  int base = blockIdx.x * TILE;
  hist[t] = 0;
  __syncthreads();
  int s[16], c[16];
#pragma unroll
  for (int i = 0; i < 16; ++i) {
    int e = base + i * 256 + t;
    if (e < E) {
      s[i] = ei[e];
      c[i] = ei[E + e];
      atomicAdd(&hist[c[i] >> 9], 1);
    } else {
      c[i] = -1;
    }
  }
  __syncthreads();
  int h = hist[t];
  scn[t] = h;
  __syncthreads();
  for (int off = 1; off < 256; off <<= 1) {
    int v = (t >= off) ? scn[t - off] : 0;
    __syncthreads();
    scn[t] += v;
    __syncthreads();
  }
  excl[t] = scn[t] - h;
  gb[t] = (h > 0) ? atomicAdd(&bcur[t], h) : 0;
  __syncthreads();
  hist[t] = excl[t];  // reuse as local placement cursor
  __syncthreads();
#pragma unroll
  for (int i = 0; i < 16; ++i) {
    if (c[i] >= 0) {
      int b = c[i] >> 9;
      int p = atomicAdd(&hist[b], 1);
      stg[p] = make_int2(s[i], c[i]);
      lb[p] = (unsigned char)b;
    }
  }
  __syncthreads();
  int cntE = min(TILE, E - base);
#pragma unroll
  for (int i = 0; i < 16; ++i) {
    int p = i * 256 + t;
    if (p < cntE) {
      int b = lb[p];
      barr[gb[b] + (p - excl[b])] = stg[p];
    }
  }
}

// ---------------- bucket-level exclusive prefix (nbuck <= 256), 1 block ------
__global__ void k_bscan(const int* __restrict__ bcur, int* __restrict__ bstart,
                        int nbuck, int* __restrict__ rowptr, int N, int E) {
  __shared__ int s[256];
  int t = threadIdx.x;
  int v = (t < nbuck) ? (bcur[t] - t * BCAP) : 0;
  s[t] = v;
  __syncthreads();
  for (int off = 1; off < 256; off <<= 1) {
    int tv = (t >= off) ? s[t - off] : 0;
    __syncthreads();
    s[t] += tv;
    __syncthreads();
  }
  if (t < nbuck) bstart[t] = s[t] - v;
  if (t == 0) rowptr[N] = E;
}

// ---------------- pass B: bucket -> CSR; also emits rowptr & dinv ------------
__global__ __launch_bounds__(512) void k_finalize(const int* __restrict__ bcur,
                                                  const int* __restrict__ bstart,
                                                  const int2* __restrict__ barr,
                                                  int* __restrict__ rowptr,
                                                  float* __restrict__ dinv,
                                                  int* __restrict__ ed4, int N) {
  __shared__ int cnt[512];
  __shared__ int sbuf[512];
  __shared__ int cur[512];
  int b = blockIdx.x;
  int node0 = b << 9;
  int nn = min(512, N - node0);
  int t = threadIdx.x;
  cnt[t] = 0;
  __syncthreads();
  int m = bcur[b] - b * BCAP;  // edges in this bucket
  int src = b * BCAP;
  int bst = bstart[b];
  for (int i = t; i < m; i += 512) atomicAdd(&cnt[barr[src + i].y - node0], 1);
  __syncthreads();
  int v = cnt[t];
  sbuf[t] = v;
  __syncthreads();
  for (int off = 1; off < 512; off <<= 1) {
    int tv = (t >= off) ? sbuf[t - off] : 0;
    __syncthreads();
    sbuf[t] += tv;
    __syncthreads();
  }
  int excl = sbuf[t] - v;
  if (t < nn) {
    rowptr[node0 + t] = bst + excl;
    dinv[node0 + t] = rsqrtf((float)v + 1.0f);
  }
  cur[t] = bst + excl;
  __syncthreads();
  for (int i = t; i < m; i += 512) {
    int2 q = barr[src + i];
    int slot = atomicAdd(&cur[q.y - node0], 1);
    ed4[slot] = q.x;
  }
}

// ---------------- W pack: split fp32 W into bf16 hi/lo, MFMA B-frag layout ----
__global__ void k_prep_w(const float* __restrict__ W, short* __restrict__ Whp,
                         short* __restrict__ Wlp) {
  int i = blockIdx.x * 256 + threadIdx.x;  // 0..16383
  int j = i & 7;
  int lane = (i >> 3) & 63;
  int cg = (i >> 9) & 3;
  int kc = i >> 11;
  int k = kc * 32 + (lane >> 4) * 8 + j;
  int col = cg * 16 + (lane & 15);
  float w = W[k * 64 + col];
  unsigned u = __float_as_uint(w);
  unsigned hbits = u & 0xFFFF0000u;  // truncate: residual captured exactly by lo
  Whp[i] = (short)(hbits >> 16);
  Wlp[i] = (short)f2bf(w - __uint_as_float(hbits));
}

// ---------------- h = relu(x @ W1 + b1), split-precision bf16 MFMA -----------
// MLP-pipeline version: 512 blocks x 4 waves = 2048 persistent-ish waves.
// Each wave grid-strides over 16-row tiles with TWO named x register sets:
// tile t+1's 16 global loads are issued BEFORE tile t's compute, so every
// wave keeps ~16 loads in flight continuously (Little's law fix for the
// burst-then-silent pattern measured at 0.78 TB/s HBM read).
// Wh staged once in LDS; Wl read per-tile from L2-hot global. Epilogue stages
// C through a PER-WAVE private LDS slice (same-wave DS ordering -> no
// __syncthreads in the loop), then coalesced full-line writeout.
#define GEMM_COMPUTE_EPI(XA, XB, T)                                              \
  {                                                                              \
    f32x4 acc[4];                                                                \
    _Pragma("unroll") for (int cg = 0; cg < 4; ++cg) acc[cg] =                   \
        (f32x4){0.f, 0.f, 0.f, 0.f};                                             \
    _Pragma("unroll") for (int kc = 0; kc < 8; ++kc) {                           \
      float f[8] = {XA[kc].x, XA[kc].y, XA[kc].z, XA[kc].w,                      \
                    XB[kc].x, XB[kc].y, XB[kc].z, XB[kc].w};                     \
      bf16x8 xh, xl;                                                             \
      _Pragma("unroll") for (int j = 0; j < 8; ++j) {                            \
        unsigned u_ = __float_as_uint(f[j]);                                     \
        unsigned hb_ = u_ & 0xFFFF0000u;                                         \
        xh[j] = (short)(hb_ >> 16);                                              \
        xl[j] = (short)f2bf(f[j] - __uint_as_float(hb_));                        \
      }                                                                          \
      _Pragma("unroll") for (int cg = 0; cg < 4; ++cg) {                         \
        const bf16x8 wh = *(const bf16x8*)&WhS[((kc * 4 + cg) * 64 + lane) * 8]; \
        const bf16x8 wl = *(const bf16x8*)&Wlp[((kc * 4 + cg) * 64 + lane) * 8]; \
        acc[cg] = __builtin_amdgcn_mfma_f32_16x16x32_bf16(xh, wh, acc[cg], 0, 0, 0); \
        acc[cg] = __builtin_amdgcn_mfma_f32_16x16x32_bf16(xl, wh, acc[cg], 0, 0, 0); \
        acc[cg] = __builtin_amdgcn_mfma_f32_16x16x32_bf16(xh, wl, acc[cg], 0, 0, 0); \
      }                                                                          \
    }                                                                            \
    _Pragma("unroll") for (int cg = 0; cg < 4; ++cg) {                           \
      _Pragma("unroll") for (int r = 0; r < 4; ++r) {                            \
        Cw[(q * 4 + r) * 68 + cg * 16 + rr] = fmaxf(acc[cg][r] + bias[cg], 0.f); \
      }                                                                          \
    }                                                                            \
    {                                                                            \
      int lr = lane >> 2;                                                        \
      int cq = lane & 3;                                                         \
      long grow = (long)(T)*16 + lr;                                             \
      if (grow < N) {                                                            \
        union F4U { f32x4 v; float f[4]; };                                      \
        const float* cp = &Cw[lr * 68 + cq * 16];                                \
        F4U w0, w1, w2, w3;                                                      \
        w0.v = *(const f32x4*)cp;                                                \
        w1.v = *(const f32x4*)(cp + 4);                                          \
        w2.v = *(const f32x4*)(cp + 8);                                          \
        w3.v = *(const f32x4*)(cp + 12);                                         \
        size_t ob = (size_t)grow * 64 + cq * 16;                                 \
        float* hp = h + ob;                                                      \
        *(f32x4*)hp = w0.v;                                                      \
        *(f32x4*)(hp + 4) = w1.v;                                                \
        *(f32x4*)(hp + 8) = w2.v;                                                \
        *(f32x4*)(hp + 12) = w3.v;                                               \
        float dv = dinv[grow];                                                   \
        uint4 ub, ub2, uz, uz2;                                                  \
        ub.x = (unsigned)f2bf(w0.f[0]) | ((unsigned)f2bf(w0.f[1]) << 16);        \
        ub.y = (unsigned)f2bf(w0.f[2]) | ((unsigned)f2bf(w0.f[3]) << 16);        \
        ub.z = (unsigned)f2bf(w1.f[0]) | ((unsigned)f2bf(w1.f[1]) << 16);        \
        ub.w = (unsigned)f2bf(w1.f[2]) | ((unsigned)f2bf(w1.f[3]) << 16);        \
        ub2.x = (unsigned)f2bf(w2.f[0]) | ((unsigned)f2bf(w2.f[1]) << 16);       \
        ub2.y = (unsigned)f2bf(w2.f[2]) | ((unsigned)f2bf(w2.f[3]) << 16);       \
        ub2.z = (unsigned)f2bf(w3.f[0]) | ((unsigned)f2bf(w3.f[1]) << 16);       \
        ub2.w = (unsigned)f2bf(w3.f[2]) | ((unsigned)f2bf(w3.f[3]) << 16);       \
        uz.x = (unsigned)f2bf(dv * w0.f[0]) | ((unsigned)f2bf(dv * w0.f[1]) << 16); \
        uz.y = (unsigned)f2bf(dv * w0.f[2]) | ((unsigned)f2bf(dv * w0.f[3]) << 16); \
        uz.z = (unsigned)f2bf(dv * w1.f[0]) | ((unsigned)f2bf(dv * w1.f[1]) << 16); \
        uz.w = (unsigned)f2bf(dv * w1.f[2]) | ((unsigned)f2bf(dv * w1.f[3]) << 16); \
        uz2.x = (unsigned)f2bf(dv * w2.f[0]) | ((unsigned)f2bf(dv * w2.f[1]) << 16); \
        uz2.y = (unsigned)f2bf(dv * w2.f[2]) | ((unsigned)f2bf(dv * w2.f[3]) << 16); \
        uz2.z = (unsigned)f2bf(dv * w3.f[0]) | ((unsigned)f2bf(dv * w3.f[1]) << 16); \
        uz2.w = (unsigned)f2bf(dv * w3.f[2]) | ((unsigned)f2bf(dv * w3.f[3]) << 16); \
        *(uint4*)(hb + ob) = ub;                                                 \
        *(uint4*)(hb + ob + 8) = ub2;                                            \
        *(uint4*)(zs0 + ob) = uz;                                                \
        *(uint4*)(zs0 + ob + 8) = uz2;                                           \
      }                                                                          \
    }                                                                            \
  }

#define GEMM_PREFETCH(XA, XB, T)                                                 \
  {                                                                              \
    long arow_ = (long)(T)*16 + rr;                                              \
    if (arow_ > N - 1) arow_ = N - 1;                                            \
    const float* xr_ = x + arow_ * 256 + q * 8;                                  \
    _Pragma("unroll") for (int kc = 0; kc < 8; ++kc) {                           \
      XA[kc] = *(const f32x4*)(xr_ + kc * 32);                                   \
      XB[kc] = *(const f32x4*)(xr_ + kc * 32 + 4);                               \
    }                                                                            \
  }

__global__ __launch_bounds__(256, 2) void k_gemm_mfma(const float* __restrict__ x,
                                                      const short* __restrict__ Whp,
                                                      const short* __restrict__ Wlp,
                                                      const float* __restrict__ b,
                                                      const float* __restrict__ dinv,
                                                      float* __restrict__ h,
                                                      bf16_t* __restrict__ hb,
                                                      bf16_t* __restrict__ zs0, int N) {
  __shared__ __align__(16) char smem[50176];  // 32KB Wh + 4 x (16x68 f32) slices
  short* WhS = (short*)smem;
  int tid = threadIdx.x;
  for (int i = tid; i < 2048; i += 256) {
    ((int4*)WhS)[i] = ((const int4*)Whp)[i];
  }
  __syncthreads();
  int wid = tid >> 6;
  int lane = tid & 63;
  int rr = lane & 15;
  int q = lane >> 4;
  float* Cw = (float*)(smem + 32768) + wid * 1088;  // per-wave private slice

  float bias[4];
#pragma unroll
  for (int cg = 0; cg < 4; ++cg) bias[cg] = b[cg * 16 + rr];

  int ntiles = (N + 15) >> 4;
  int gw = blockIdx.x * 4 + wid;  // 0..2047
  const int stride = 2048;

  f32x4 xaA[8], xbA[8], xaB[8], xbB[8];
  int t0 = gw;
  if (t0 < ntiles) {
    GEMM_PREFETCH(xaA, xbA, t0);
    while (true) {
      int t1 = t0 + stride;
      if (t1 < ntiles) GEMM_PREFETCH(xaB, xbB, t1);
      GEMM_COMPUTE_EPI(xaA, xbA, t0);
      if (t1 >= ntiles) break;
      int t2 = t1 + stride;
      if (t2 < ntiles) GEMM_PREFETCH(xaA, xbA, t2);
      GEMM_COMPUTE_EPI(xaB, xbB, t1);
      if (t2 >= ntiles) break;
      t0 = t2;
    }
  }
}

// ---------------- propagation: 8 lanes/node, bf16x8 gathers ------------------
template <int LAST>
__global__ __launch_bounds__(256) void k_prop(const int* __restrict__ rowptr,
                                              const int* __restrict__ ed4,
                                              const float* __restrict__ dinv,
                                              const bf16_t* __restrict__ zin,
                                              const bf16_t* __restrict__ hbi,
                                              const float* __restrict__ hf,
                                              void* __restrict__ zout_, int N) {
  int tid = threadIdx.x;
  int lane = tid & 63;
  int u = lane & 7;       // channel octet: channels u*8 .. u*8+7
  int g = lane >> 3;      // node sub-index within wave (0..7)
  int gbase = lane & 56;  // first lane of this group
  int node = blockIdx.x * 32 + (tid >> 6) * 8 + g;
  bool live = node < N;
  if (!live) node = N - 1;  // clamp; stores guarded
  int beg = rowptr[node];
  int m = rowptr[node + 1] - beg;
  float dvc = dinv[node];
  size_t base = (size_t)node * 64 + u * 8;

  union V { bf16x8 v; unsigned d[4]; };
  V zs;
  zs.v = *(const bf16x8*)(zin + base);  // self term (already dinv-scaled)
  float a0 = __uint_as_float(zs.d[0] << 16);
  float a1 = __uint_as_float(zs.d[0] & 0xFFFF0000u);
  float a2 = __uint_as_float(zs.d[1] << 16);
  float a3 = __uint_as_float(zs.d[1] & 0xFFFF0000u);
  float a4 = __uint_as_float(zs.d[2] << 16);
  float a5 = __uint_as_float(zs.d[2] & 0xFFFF0000u);
  float a6 = __uint_as_float(zs.d[3] << 16);
  float a7 = __uint_as_float(zs.d[3] & 0xFFFF0000u);

  int full = m & ~7;
  for (int off = 0; off < full; off += 8) {
    int ev = ed4[beg + off + u];
#pragma unroll
    for (int j = 0; j < 8; ++j) {
      int src = __shfl(ev, gbase + j, 64);
      V z;
      z.v = *(const bf16x8*)(zin + (size_t)src * 64 + u * 8);
      a0 += __uint_as_float(z.d[0] << 16);
      a1 += __uint_as_float(z.d[0] & 0xFFFF0000u);
      a2 += __uint_as_float(z.d[1] << 16);
      a3 += __uint_as_float(z.d[1] & 0xFFFF0000u);
      a4 += __uint_as_float(z.d[2] << 16);
      a5 += __uint_as_float(z.d[2] & 0xFFFF0000u);
      a6 += __uint_as_float(z.d[3] << 16);
      a7 += __uint_as_float(z.d[3] & 0xFFFF0000u);
    }
  }
  int rem = m - full;
  if (rem > 0) {
    int ev = (u < rem) ? ed4[beg + full + u] : 0;
    for (int j = 0; j < rem; ++j) {
      int src = __shfl(ev, gbase + j, 64);
      V z;
      z.v = *(const bf16x8*)(zin + (size_t)src * 64 + u * 8);
      a0 += __uint_as_float(z.d[0] << 16);
      a1 += __uint_as_float(z.d[0] & 0xFFFF0000u);
      a2 += __uint_as_float(z.d[1] << 16);
      a3 += __uint_as_float(z.d[1] & 0xFFFF0000u);
      a4 += __uint_as_float(z.d[2] << 16);
      a5 += __uint_as_float(z.d[2] & 0xFFFF0000u);
      a6 += __uint_as_float(z.d[3] << 16);
      a7 += __uint_as_float(z.d[3] & 0xFFFF0000u);
    }
  }

  float sca = 0.9f * dvc;
  if (LAST) {
    const float* hp = hf + base;
    f32x4 h0 = *(const f32x4*)hp;
    f32x4 h1 = *(const f32x4*)(hp + 4);
    f32x4 r0, r1;
    r0.x = sca * a0 + 0.1f * h0.x;
    r0.y = sca * a1 + 0.1f * h0.y;
    r0.z = sca * a2 + 0.1f * h0.z;
    r0.w = sca * a3 + 0.1f * h0.w;
    r1.x = sca * a4 + 0.1f * h1.x;
    r1.y = sca * a5 + 0.1f * h1.y;
    r1.z = sca * a6 + 0.1f * h1.z;
    r1.w = sca * a7 + 0.1f * h1.w;
    if (live) {
      float* zp = (float*)zout_ + base;
      *(f32x4*)zp = r0;
      *(f32x4*)(zp + 4) = r1;
    }
  } else {
    V hv;
    hv.v = *(const bf16x8*)(hbi + base);
    float r0 = dvc * (sca * a0 + 0.1f * __uint_as_float(hv.d[0] << 16));
    float r1 = dvc * (sca * a1 + 0.1f * __uint_as_float(hv.d[0] & 0xFFFF0000u));
    float r2 = dvc * (sca * a2 + 0.1f * __uint_as_float(hv.d[1] << 16));
    float r3 = dvc * (sca * a3 + 0.1f * __uint_as_float(hv.d[1] & 0xFFFF0000u));
    float r4 = dvc * (sca * a4 + 0.1f * __uint_as_float(hv.d[2] << 16));
    float r5 = dvc * (sca * a5 + 0.1f * __uint_as_float(hv.d[2] & 0xFFFF0000u));
    float r6 = dvc * (sca * a6 + 0.1f * __uint_as_float(hv.d[3] << 16));
    float r7 = dvc * (sca * a7 + 0.1f * __uint_as_float(hv.d[3] & 0xFFFF0000u));
    uint4 o;
    o.x = (unsigned)f2bf(r0) | (((unsigned)f2bf(r1)) << 16);
    o.y = (unsigned)f2bf(r2) | (((unsigned)f2bf(r3)) << 16);
    o.z = (unsigned)f2bf(r4) | (((unsigned)f2bf(r5)) << 16);
    o.w = (unsigned)f2bf(r6) | (((unsigned)f2bf(r7)) << 16);
    if (live) *(uint4*)((bf16_t*)zout_ + base) = o;
  }
}

// ---------------- launch ----------------

extern "C" void kernel_launch(void* const* d_in, const int* in_sizes, int n_in,
                              void* d_out, int out_size, void* d_ws, size_t ws_size,
                              hipStream_t stream) {
  const float* x = (const float*)d_in[0];
  const int* ei = (const int*)d_in[1];  // int32 per harness contract
  const float* W1 = (const float*)d_in[2];
  const float* b1 = (const float*)d_in[3];
  float* zfinal = (float*)d_out;

  int OUT = in_sizes[3];        // 64
  int IN = in_sizes[2] / OUT;   // 256
  int N = in_sizes[0] / IN;     // 100000
  int E = in_sizes[1] / 2;      // 1600000

  char* ws = (char*)d_ws;
  size_t off = 0;
  auto alloc = [&](size_t bytes) -> char* {
    char* p = ws + off;
    off = (off + bytes + 255) & ~(size_t)255;
    return p;
  };
  int nbuck = (N + 511) >> 9;  // 196
  float* h = (float*)alloc((size_t)N * OUT * 4);       // 25.6 MB
  bf16_t* hb = (bf16_t*)alloc((size_t)N * OUT * 2);    // 12.8 MB
  bf16_t* zs0 = (bf16_t*)alloc((size_t)N * OUT * 2);   // 12.8 MB
  bf16_t* z0 = (bf16_t*)alloc((size_t)N * OUT * 2);    // 12.8 MB
  bf16_t* z1 = (bf16_t*)alloc((size_t)N * OUT * 2);    // 12.8 MB
  int2* barr = (int2*)alloc((size_t)nbuck * BCAP * 8); // 25.7 MB
  int* ed4 = (int*)alloc((size_t)E * 4 + 64);          // 6.4 MB
  short* Whp = (short*)alloc(16384 * 2);
  short* Wlp = (short*)alloc(16384 * 2);
  int* rowptr = (int*)alloc((size_t)(N + 1) * 4);
  float* dinv = (float*)alloc((size_t)N * 4);
  int* bcur = (int*)alloc(256 * 4);
  int* bstart = (int*)alloc(256 * 4);
  (void)ws_size;

  hipLaunchKernelGGL(k_initb, dim3(1), dim3(256), 0, stream, bcur, nbuck);
  hipLaunchKernelGGL(k_bucket, dim3((E + TILE - 1) / TILE), dim3(256), 0, stream, ei, E,
                     bcur, barr);
  hipLaunchKernelGGL(k_bscan, dim3(1), dim3(256), 0, stream, bcur, bstart, nbuck, rowptr,
                     N, E);
  hipLaunchKernelGGL(k_finalize, dim3(nbuck), dim3(512), 0, stream, bcur, bstart, barr,
                     rowptr, dinv, ed4, N);
  hipLaunchKernelGGL(k_prep_w, dim3(64), dim3(256), 0, stream, W1, Whp, Wlp);
  hipLaunchKernelGGL(k_gemm_mfma, dim3(512), dim3(256), 0, stream, x, Whp,
                     Wlp, b1, dinv, h, hb, zs0, N);

  dim3 pgrid((N + 31) / 32);  // 256 threads = 4 waves x 8 nodes = 32 nodes/block
  const bf16_t* zi = zs0;
  bf16_t* zb[2] = {z0, z1};
  for (int it = 0; it < KITER - 1; ++it) {
    bf16_t* zo = zb[it & 1];
    hipLaunchKernelGGL((k_prop<0>), pgrid, dim3(256), 0, stream, rowptr, ed4, dinv, zi,
                       hb, h, (void*)zo, N);
    zi = zo;
  }
  hipLaunchKernelGGL((k_prop<1>), pgrid, dim3(256), 0, stream, rowptr, ed4, dinv, zi, hb,
                     h, (void*)zfinal, N);
}

// Round 8
// 458.792 us; speedup vs baseline: 1.0036x; 1.0036x over previous
//
#include <hip/hip_runtime.h>

#define KITER 10
#define TILE 4096
#define BCAP 16384  // bucket staging capacity (expected 8192/bucket, +90 sigma)
typedef unsigned short bf16_t;
typedef __attribute__((ext_vector_type(4))) short bf16x4;
typedef __attribute__((ext_vector_type(8))) short bf16x8;
typedef __attribute__((ext_vector_type(4))) float f32x4;

__device__ __forceinline__ float bf2f(bf16_t u) {
  union { unsigned u; float f; } cv;
  cv.u = ((unsigned)u) << 16;
  return cv.f;
}
__device__ __forceinline__ bf16_t f2bf(float f) {
  unsigned u = __float_as_uint(f);
  unsigned r = (u + 0x7FFFu + ((u >> 16) & 1u)) >> 16;  // round-nearest-even
  return (bf16_t)r;
}

// ---------------- bucket cursor init: bcur[b] = b*BCAP ----------------
__global__ void k_initb(int* __restrict__ bcur, int nbuck) {
  int i = threadIdx.x;
  if (i < nbuck) bcur[i] = i * BCAP;
}

// ---------------- bucket sort pass A: tile -> per-bucket coalesced runs ------
__global__ __launch_bounds__(256) void k_bucket(const int* __restrict__ ei, int E,
                                                int* __restrict__ bcur,
                                                int2* __restrict__ barr) {
  __shared__ int hist[256];
  __shared__ int scn[256];
  __shared__ int excl[256];
  __shared__ int gb[256];
  __shared__ unsigned char lb[TILE];
  __shared__ int2 stg[TILE];
  int t = threadIdx.x;
  int base = blockIdx.x * TILE;
  hist[t] = 0;
  __syncthreads();
  int s[16], c[16];
#pragma unroll
  for (int i = 0; i < 16; ++i) {
    int e = base + i * 256 + t;
    if (e < E) {
      s[i] = ei[e];
      c[i] = ei[E + e];
      atomicAdd(&hist[c[i] >> 9], 1);
    } else {
      c[i] = -1;
    }
  }
  __syncthreads();
  int h = hist[t];
  scn[t] = h;
  __syncthreads();
  for (int off = 1; off < 256; off <<= 1) {
    int v = (t >= off) ? scn[t - off] : 0;
    __syncthreads();
    scn[t] += v;
    __syncthreads();
  }
  excl[t] = scn[t] - h;
  gb[t] = (h > 0) ? atomicAdd(&bcur[t], h) : 0;
  __syncthreads();
  hist[t] = excl[t];  // reuse as local placement cursor
  __syncthreads();
#pragma unroll
  for (int i = 0; i < 16; ++i) {
    if (c[i] >= 0) {
      int b = c[i] >> 9;
      int p = atomicAdd(&hist[b], 1);
      stg[p] = make_int2(s[i], c[i]);
      lb[p] = (unsigned char)b;
    }
  }
  __syncthreads();
  int cntE = min(TILE, E - base);
#pragma unroll
  for (int i = 0; i < 16; ++i) {
    int p = i * 256 + t;
    if (p < cntE) {
      int b = lb[p];
      barr[gb[b] + (p - excl[b])] = stg[p];
    }
  }
}

// ---------------- bucket-level exclusive prefix (nbuck <= 256), 1 block ------
__global__ void k_bscan(const int* __restrict__ bcur, int* __restrict__ bstart,
                        int nbuck, int* __restrict__ rowptr, int N, int E) {
  __shared__ int s[256];
  int t = threadIdx.x;
  int v = (t < nbuck) ? (bcur[t] - t * BCAP) : 0;
  s[t] = v;
  __syncthreads();
  for (int off = 1; off < 256; off <<= 1) {
    int tv = (t >= off) ? s[t - off] : 0;
    __syncthreads();
    s[t] += tv;
    __syncthreads();
  }
  if (t < nbuck) bstart[t] = s[t] - v;
  if (t == 0) rowptr[N] = E;
}

// ---------------- pass B: bucket -> CSR; also emits rowptr & dinv ------------
__global__ __launch_bounds__(512) void k_finalize(const int* __restrict__ bcur,
                                                  const int* __restrict__ bstart,
                                                  const int2* __restrict__ barr,
                                                  int* __restrict__ rowptr,
                                                  float* __restrict__ dinv,
                                                  int* __restrict__ ed4, int N) {
  __shared__ int cnt[512];
  __shared__ int sbuf[512];
  __shared__ int cur[512];
  int b = blockIdx.x;
  int node0 = b << 9;
  int nn = min(512, N - node0);
  int t = threadIdx.x;
  cnt[t] = 0;
  __syncthreads();
  int m = bcur[b] - b * BCAP;  // edges in this bucket
  int src = b * BCAP;
  int bst = bstart[b];
  for (int i = t; i < m; i += 512) atomicAdd(&cnt[barr[src + i].y - node0], 1);
  __syncthreads();
  int v = cnt[t];
  sbuf[t] = v;
  __syncthreads();
  for (int off = 1; off < 512; off <<= 1) {
    int tv = (t >= off) ? sbuf[t - off] : 0;
    __syncthreads();
    sbuf[t] += tv;
    __syncthreads();
  }
  int excl = sbuf[t] - v;
  if (t < nn) {
    rowptr[node0 + t] = bst + excl;
    dinv[node0 + t] = rsqrtf((float)v + 1.0f);
  }
  cur[t] = bst + excl;
  __syncthreads();
  for (int i = t; i < m; i += 512) {
    int2 q = barr[src + i];
    int slot = atomicAdd(&cur[q.y - node0], 1);
    ed4[slot] = q.x;
  }
}

// ---------------- W pack: split fp32 W into bf16 hi/lo, MFMA B-frag layout ----
__global__ void k_prep_w(const float* __restrict__ W, short* __restrict__ Whp,
                         short* __restrict__ Wlp) {
  int i = blockIdx.x * 256 + threadIdx.x;  // 0..16383
  int j = i & 7;
  int lane = (i >> 3) & 63;
  int cg = (i >> 9) & 3;
  int kc = i >> 11;
  int k = kc * 32 + (lane >> 4) * 8 + j;
  int col = cg * 16 + (lane & 15);
  float w = W[k * 64 + col];
  unsigned u = __float_as_uint(w);
  unsigned hbits = u & 0xFFFF0000u;  // truncate: residual captured exactly by lo
  Whp[i] = (short)(hbits >> 16);
  Wlp[i] = (short)f2bf(w - __uint_as_float(hbits));
}

// ---------------- h = relu(x @ W1 + b1), split-precision bf16 MFMA -----------
// MLP-pipeline version: 512 blocks x 4 waves = 2048 persistent-ish waves.
// Each wave grid-strides over 16-row tiles with TWO named x register sets:
// tile t+1's 16 global loads are issued BEFORE tile t's compute, so every
// wave keeps ~16 loads in flight continuously (Little's law fix for the
// burst-then-silent pattern measured at 0.78 TB/s HBM read).
// Wh staged once in LDS; Wl read per-tile from L2-hot global. Epilogue stages
// C through a PER-WAVE private LDS slice (same-wave DS ordering -> no
// __syncthreads in the loop), then coalesced full-line writeout.
#define GEMM_COMPUTE_EPI(XA, XB, T)                                              \
  {                                                                              \
    f32x4 acc[4];                                                                \
    _Pragma("unroll") for (int cg = 0; cg < 4; ++cg) acc[cg] =                   \
        (f32x4){0.f, 0.f, 0.f, 0.f};                                             \
    _Pragma("unroll") for (int kc = 0; kc < 8; ++kc) {                           \
      float f[8] = {XA[kc].x, XA[kc].y, XA[kc].z, XA[kc].w,                      \
                    XB[kc].x, XB[kc].y, XB[kc].z, XB[kc].w};                     \
      bf16x8 xh, xl;                                                             \
      _Pragma("unroll") for (int j = 0; j < 8; ++j) {                            \
        unsigned u_ = __float_as_uint(f[j]);                                     \
        unsigned hb_ = u_ & 0xFFFF0000u;                                         \
        xh[j] = (short)(hb_ >> 16);                                              \
        xl[j] = (short)f2bf(f[j] - __uint_as_float(hb_));                        \
      }                                                                          \
      _Pragma("unroll") for (int cg = 0; cg < 4; ++cg) {                         \
        const bf16x8 wh = *(const bf16x8*)&WhS[((kc * 4 + cg) * 64 + lane) * 8]; \
        const bf16x8 wl = *(const bf16x8*)&Wlp[((kc * 4 + cg) * 64 + lane) * 8]; \
        acc[cg] = __builtin_amdgcn_mfma_f32_16x16x32_bf16(xh, wh, acc[cg], 0, 0, 0); \
        acc[cg] = __builtin_amdgcn_mfma_f32_16x16x32_bf16(xl, wh, acc[cg], 0, 0, 0); \
        acc[cg] = __builtin_amdgcn_mfma_f32_16x16x32_bf16(xh, wl, acc[cg], 0, 0, 0); \
      }                                                                          \
    }                                                                            \
    _Pragma("unroll") for (int cg = 0; cg < 4; ++cg) {                           \
      _Pragma("unroll") for (int r = 0; r < 4; ++r) {                            \
        Cw[(q * 4 + r) * 68 + cg * 16 + rr] = fmaxf(acc[cg][r] + bias[cg], 0.f); \
      }                                                                          \
    }                                                                            \
    {                                                                            \
      int lr = lane >> 2;                                                        \
      int cq = lane & 3;                                                         \
      long grow = (long)(T)*16 + lr;                                             \
      if (grow < N) {                                                            \
        union F4U { f32x4 v; float f[4]; };                                      \
        const float* cp = &Cw[lr * 68 + cq * 16];                                \
        F4U w0, w1, w2, w3;                                                      \
        w0.v = *(const f32x4*)cp;                                                \
        w1.v = *(const f32x4*)(cp + 4);                                          \
        w2.v = *(const f32x4*)(cp + 8);                                          \
        w3.v = *(const f32x4*)(cp + 12);                                         \
        size_t ob = (size_t)grow * 64 + cq * 16;                                 \
        float* hp = h + ob;                                                      \
        *(f32x4*)hp = w0.v;                                                      \
        *(f32x4*)(hp + 4) = w1.v;                                                \
        *(f32x4*)(hp + 8) = w2.v;                                                \
        *(f32x4*)(hp + 12) = w3.v;                                               \
        float dv = dinv[grow];                                                   \
        uint4 ub, ub2, uz, uz2;                                                  \
        ub.x = (unsigned)f2bf(w0.f[0]) | ((unsigned)f2bf(w0.f[1]) << 16);        \
        ub.y = (unsigned)f2bf(w0.f[2]) | ((unsigned)f2bf(w0.f[3]) << 16);        \
        ub.z = (unsigned)f2bf(w1.f[0]) | ((unsigned)f2bf(w1.f[1]) << 16);        \
        ub.w = (unsigned)f2bf(w1.f[2]) | ((unsigned)f2bf(w1.f[3]) << 16);        \
        ub2.x = (unsigned)f2bf(w2.f[0]) | ((unsigned)f2bf(w2.f[1]) << 16);       \
        ub2.y = (unsigned)f2bf(w2.f[2]) | ((unsigned)f2bf(w2.f[3]) << 16);       \
        ub2.z = (unsigned)f2bf(w3.f[0]) | ((unsigned)f2bf(w3.f[1]) << 16);       \
        ub2.w = (unsigned)f2bf(w3.f[2]) | ((unsigned)f2bf(w3.f[3]) << 16);       \
        uz.x = (unsigned)f2bf(dv * w0.f[0]) | ((unsigned)f2bf(dv * w0.f[1]) << 16); \
        uz.y = (unsigned)f2bf(dv * w0.f[2]) | ((unsigned)f2bf(dv * w0.f[3]) << 16); \
        uz.z = (unsigned)f2bf(dv * w1.f[0]) | ((unsigned)f2bf(dv * w1.f[1]) << 16); \
        uz.w = (unsigned)f2bf(dv * w1.f[2]) | ((unsigned)f2bf(dv * w1.f[3]) << 16); \
        uz2.x = (unsigned)f2bf(dv * w2.f[0]) | ((unsigned)f2bf(dv * w2.f[1]) << 16); \
        uz2.y = (unsigned)f2bf(dv * w2.f[2]) | ((unsigned)f2bf(dv * w2.f[3]) << 16); \
        uz2.z = (unsigned)f2bf(dv * w3.f[0]) | ((unsigned)f2bf(dv * w3.f[1]) << 16); \
        uz2.w = (unsigned)f2bf(dv * w3.f[2]) | ((unsigned)f2bf(dv * w3.f[3]) << 16); \
        *(uint4*)(hb + ob) = ub;                                                 \
        *(uint4*)(hb + ob + 8) = ub2;                                            \
        *(uint4*)(zs0 + ob) = uz;                                                \
        *(uint4*)(zs0 + ob + 8) = uz2;                                           \
      }                                                                          \
    }                                                                            \
  }

#define GEMM_PREFETCH(XA, XB, T)                                                 \
  {                                                                              \
    long arow_ = (long)(T)*16 + rr;                                              \
    if (arow_ > N - 1) arow_ = N - 1;                                            \
    const float* xr_ = x + arow_ * 256 + q * 8;                                  \
    _Pragma("unroll") for (int kc = 0; kc < 8; ++kc) {                           \
      XA[kc] = *(const f32x4*)(xr_ + kc * 32);                                   \
      XB[kc] = *(const f32x4*)(xr_ + kc * 32 + 4);                               \
    }                                                                            \
  }

__global__ __launch_bounds__(256, 2) void k_gemm_mfma(const float* __restrict__ x,
                                                      const short* __restrict__ Whp,
                                                      const short* __restrict__ Wlp,
                                                      const float* __restrict__ b,
                                                      const float* __restrict__ dinv,
                                                      float* __restrict__ h,
                                                      bf16_t* __restrict__ hb,
                                                      bf16_t* __restrict__ zs0, int N) {
  __shared__ __align__(16) char smem[50176];  // 32KB Wh + 4 x (16x68 f32) slices
  short* WhS = (short*)smem;
  int tid = threadIdx.x;
  for (int i = tid; i < 2048; i += 256) {
    ((int4*)WhS)[i] = ((const int4*)Whp)[i];
  }
  __syncthreads();
  int wid = tid >> 6;
  int lane = tid & 63;
  int rr = lane & 15;
  int q = lane >> 4;
  float* Cw = (float*)(smem + 32768) + wid * 1088;  // per-wave private slice

  float bias[4];
#pragma unroll
  for (int cg = 0; cg < 4; ++cg) bias[cg] = b[cg * 16 + rr];

  int ntiles = (N + 15) >> 4;
  int gw = blockIdx.x * 4 + wid;  // 0..2047
  const int stride = 2048;

  f32x4 xaA[8], xbA[8], xaB[8], xbB[8];
  int t0 = gw;
  if (t0 < ntiles) {
    GEMM_PREFETCH(xaA, xbA, t0);
    while (true) {
      int t1 = t0 + stride;
      if (t1 < ntiles) GEMM_PREFETCH(xaB, xbB, t1);
      GEMM_COMPUTE_EPI(xaA, xbA, t0);
      if (t1 >= ntiles) break;
      int t2 = t1 + stride;
      if (t2 < ntiles) GEMM_PREFETCH(xaA, xbA, t2);
      GEMM_COMPUTE_EPI(xaB, xbB, t1);
      if (t2 >= ntiles) break;
      t0 = t2;
    }
  }
}

// ---------------- propagation: 8 lanes/node, bf16x8 gathers ------------------
template <int LAST>
__global__ __launch_bounds__(256) void k_prop(const int* __restrict__ rowptr,
                                              const int* __restrict__ ed4,
                                              const float* __restrict__ dinv,
                                              const bf16_t* __restrict__ zin,
                                              const bf16_t* __restrict__ hbi,
                                              const float* __restrict__ hf,
                                              void* __restrict__ zout_, int N) {
  int tid = threadIdx.x;
  int lane = tid & 63;
  int u = lane & 7;       // channel octet: channels u*8 .. u*8+7
  int g = lane >> 3;      // node sub-index within wave (0..7)
  int gbase = lane & 56;  // first lane of this group
  int node = blockIdx.x * 32 + (tid >> 6) * 8 + g;
  bool live = node < N;
  if (!live) node = N - 1;  // clamp; stores guarded
  int beg = rowptr[node];
  int m = rowptr[node + 1] - beg;
  float dvc = dinv[node];
  size_t base = (size_t)node * 64 + u * 8;

  union V { bf16x8 v; unsigned d[4]; };
  V zs;
  zs.v = *(const bf16x8*)(zin + base);  // self term (already dinv-scaled)
  float a0 = __uint_as_float(zs.d[0] << 16);
  float a1 = __uint_as_float(zs.d[0] & 0xFFFF0000u);
  float a2 = __uint_as_float(zs.d[1] << 16);
  float a3 = __uint_as_float(zs.d[1] & 0xFFFF0000u);
  float a4 = __uint_as_float(zs.d[2] << 16);
  float a5 = __uint_as_float(zs.d[2] & 0xFFFF0000u);
  float a6 = __uint_as_float(zs.d[3] << 16);
  float a7 = __uint_as_float(zs.d[3] & 0xFFFF0000u);

  int full = m & ~7;
  for (int off = 0; off < full; off += 8) {
    int ev = ed4[beg + off + u];
#pragma unroll
    for (int j = 0; j < 8; ++j) {
      int src = __shfl(ev, gbase + j, 64);
      V z;
      z.v = *(const bf16x8*)(zin + (size_t)src * 64 + u * 8);
      a0 += __uint_as_float(z.d[0] << 16);
      a1 += __uint_as_float(z.d[0] & 0xFFFF0000u);
      a2 += __uint_as_float(z.d[1] << 16);
      a3 += __uint_as_float(z.d[1] & 0xFFFF0000u);
      a4 += __uint_as_float(z.d[2] << 16);
      a5 += __uint_as_float(z.d[2] & 0xFFFF0000u);
      a6 += __uint_as_float(z.d[3] << 16);
      a7 += __uint_as_float(z.d[3] & 0xFFFF0000u);
    }
  }
  int rem = m - full;
  if (rem > 0) {
    int ev = (u < rem) ? ed4[beg + full + u] : 0;
    for (int j = 0; j < rem; ++j) {
      int src = __shfl(ev, gbase + j, 64);
      V z;
      z.v = *(const bf16x8*)(zin + (size_t)src * 64 + u * 8);
      a0 += __uint_as_float(z.d[0] << 16);
      a1 += __uint_as_float(z.d[0] & 0xFFFF0000u);
      a2 += __uint_as_float(z.d[1] << 16);
      a3 += __uint_as_float(z.d[1] & 0xFFFF0000u);
      a4 += __uint_as_float(z.d[2] << 16);
      a5 += __uint_as_float(z.d[2] & 0xFFFF0000u);
      a6 += __uint_as_float(z.d[3] << 16);
      a7 += __uint_as_float(z.d[3] & 0xFFFF0000u);
    }
  }

  float sca = 0.9f * dvc;
  if (LAST) {
    const float* hp = hf + base;
    f32x4 h0 = *(const f32x4*)hp;
    f32x4 h1 = *(const f32x4*)(hp + 4);
    f32x4 r0, r1;
    r0.x = sca * a0 + 0.1f * h0.x;
    r0.y = sca * a1 + 0.1f * h0.y;
    r0.z = sca * a2 + 0.1f * h0.z;
    r0.w = sca * a3 + 0.1f * h0.w;
    r1.x = sca * a4 + 0.1f * h1.x;
    r1.y = sca * a5 + 0.1f * h1.y;
    r1.z = sca * a6 + 0.1f * h1.z;
    r1.w = sca * a7 + 0.1f * h1.w;
    if (live) {
      float* zp = (float*)zout_ + base;
      *(f32x4*)zp = r0;
      *(f32x4*)(zp + 4) = r1;
    }
  } else {
    V hv;
    hv.v = *(const bf16x8*)(hbi + base);
    float r0 = dvc * (sca * a0 + 0.1f * __uint_as_float(hv.d[0] << 16));
    float r1 = dvc * (sca * a1 + 0.1f * __uint_as_float(hv.d[0] & 0xFFFF0000u));
    float r2 = dvc * (sca * a2 + 0.1f * __uint_as_float(hv.d[1] << 16));
    float r3 = dvc * (sca * a3 + 0.1f * __uint_as_float(hv.d[1] & 0xFFFF0000u));
    float r4 = dvc * (sca * a4 + 0.1f * __uint_as_float(hv.d[2] << 16));
    float r5 = dvc * (sca * a5 + 0.1f * __uint_as_float(hv.d[2] & 0xFFFF0000u));
    float r6 = dvc * (sca * a6 + 0.1f * __uint_as_float(hv.d[3] << 16));
    float r7 = dvc * (sca * a7 + 0.1f * __uint_as_float(hv.d[3] & 0xFFFF0000u));
    uint4 o;
    o.x = (unsigned)f2bf(r0) | (((unsigned)f2bf(r1)) << 16);
    o.y = (unsigned)f2bf(r2) | (((unsigned)f2bf(r3)) << 16);
    o.z = (unsigned)f2bf(r4) | (((unsigned)f2bf(r5)) << 16);
    o.w = (unsigned)f2bf(r6) | (((unsigned)f2bf(r7)) << 16);
    if (live) *(uint4*)((bf16_t*)zout_ + base) = o;
  }
}

// ---------------- launch ----------------

extern "C" void kernel_launch(void* const* d_in, const int* in_sizes, int n_in,
                              void* d_out, int out_size, void* d_ws, size_t ws_size,
                              hipStream_t stream) {
  const float* x = (const float*)d_in[0];
  const int* ei = (const int*)d_in[1];  // int32 per harness contract
  const float* W1 = (const float*)d_in[2];
  const float* b1 = (const float*)d_in[3];
  float* zfinal = (float*)d_out;

  int OUT = in_sizes[3];        // 64
  int IN = in_sizes[2] / OUT;   // 256
  int N = in_sizes[0] / IN;     // 100000
  int E = in_sizes[1] / 2;      // 1600000

  char* ws = (char*)d_ws;
  size_t off = 0;
  auto alloc = [&](size_t bytes) -> char* {
    char* p = ws + off;
    off = (off + bytes + 255) & ~(size_t)255;
    return p;
  };
  int nbuck = (N + 511) >> 9;  // 196
  float* h = (float*)alloc((size_t)N * OUT * 4);       // 25.6 MB
  bf16_t* hb = (bf16_t*)alloc((size_t)N * OUT * 2);    // 12.8 MB
  bf16_t* zs0 = (bf16_t*)alloc((size_t)N * OUT * 2);   // 12.8 MB
  bf16_t* z0 = (bf16_t*)alloc((size_t)N * OUT * 2);    // 12.8 MB
  bf16_t* z1 = (bf16_t*)alloc((size_t)N * OUT * 2);    // 12.8 MB
  int2* barr = (int2*)alloc((size_t)nbuck * BCAP * 8); // 25.7 MB
  int* ed4 = (int*)alloc((size_t)E * 4 + 64);          // 6.4 MB
  short* Whp = (short*)alloc(16384 * 2);
  short* Wlp = (short*)alloc(16384 * 2);
  int* rowptr = (int*)alloc((size_t)(N + 1) * 4);
  float* dinv = (float*)alloc((size_t)N * 4);
  int* bcur = (int*)alloc(256 * 4);
  int* bstart = (int*)alloc(256 * 4);
  (void)ws_size;

  hipLaunchKernelGGL(k_initb, dim3(1), dim3(256), 0, stream, bcur, nbuck);
  hipLaunchKernelGGL(k_bucket, dim3((E + TILE - 1) / TILE), dim3(256), 0, stream, ei, E,
                     bcur, barr);
  hipLaunchKernelGGL(k_bscan, dim3(1), dim3(256), 0, stream, bcur, bstart, nbuck, rowptr,
                     N, E);
  hipLaunchKernelGGL(k_finalize, dim3(nbuck), dim3(512), 0, stream, bcur, bstart, barr,
                     rowptr, dinv, ed4, N);
  hipLaunchKernelGGL(k_prep_w, dim3(64), dim3(256), 0, stream, W1, Whp, Wlp);
  hipLaunchKernelGGL(k_gemm_mfma, dim3(512), dim3(256), 0, stream, x, Whp,
                     Wlp, b1, dinv, h, hb, zs0, N);

  dim3 pgrid((N + 31) / 32);  // 256 threads = 4 waves x 8 nodes = 32 nodes/block
  const bf16_t* zi = zs0;
  bf16_t* zb[2] = {z0, z1};
  for (int it = 0; it < KITER - 1; ++it) {
    bf16_t* zo = zb[it & 1];
    hipLaunchKernelGGL((k_prop<0>), pgrid, dim3(256), 0, stream, rowptr, ed4, dinv, zi,
                       hb, h, (void*)zo, N);
    zi = zo;
  }
  hipLaunchKernelGGL((k_prop<1>), pgrid, dim3(256), 0, stream, rowptr, ed4, dinv, zi, hb,
                     h, (void*)zfinal, N);
}

// Round 9
// 426.547 us; speedup vs baseline: 1.0795x; 1.0756x over previous
//
#include <hip/hip_runtime.h>

#define KITER 10
#define TILE 4096
#define BCAP 16384  // bucket staging capacity (expected 8192/bucket, +90 sigma)
typedef unsigned short bf16_t;
typedef __attribute__((ext_vector_type(4))) short bf16x4;
typedef __attribute__((ext_vector_type(8))) short bf16x8;
typedef __attribute__((ext_vector_type(4))) float f32x4;

__device__ __forceinline__ float bf2f(bf16_t u) {
  union { unsigned u; float f; } cv;
  cv.u = ((unsigned)u) << 16;
  return cv.f;
}
__device__ __forceinline__ bf16_t f2bf(float f) {
  unsigned u = __float_as_uint(f);
  unsigned r = (u + 0x7FFFu + ((u >> 16) & 1u)) >> 16;  // round-nearest-even
  return (bf16_t)r;
}

// ---------------- bucket cursor init: bcur[b] = b*BCAP ----------------
__global__ void k_initb(int* __restrict__ bcur, int nbuck) {
  int i = threadIdx.x;
  if (i < nbuck) bcur[i] = i * BCAP;
}

// ---------------- bucket sort pass A: tile -> per-bucket coalesced runs ------
__global__ __launch_bounds__(256) void k_bucket(const int* __restrict__ ei, int E,
                                                int* __restrict__ bcur,
                                                int2* __restrict__ barr) {
  __shared__ int hist[256];
  __shared__ int scn[256];
  __shared__ int excl[256];
  __shared__ int gb[256];
  __shared__ unsigned char lb[TILE];
  __shared__ int2 stg[TILE];
  int t = threadIdx.x;
  int base = blockIdx.x * TILE;
  hist[t] = 0;
  __syncthreads();
  int s[16], c[16];
#pragma unroll
  for (int i = 0; i < 16; ++i) {
    int e = base + i * 256 + t;
    if (e < E) {
      s[i] = ei[e];
      c[i] = ei[E + e];
      atomicAdd(&hist[c[i] >> 9], 1);
    } else {
      c[i] = -1;
    }
  }
  __syncthreads();
  int h = hist[t];
  scn[t] = h;
  __syncthreads();
  for (int off = 1; off < 256; off <<= 1) {
    int v = (t >= off) ? scn[t - off] : 0;
    __syncthreads();
    scn[t] += v;
    __syncthreads();
  }
  excl[t] = scn[t] - h;
  gb[t] = (h > 0) ? atomicAdd(&bcur[t], h) : 0;
  __syncthreads();
  hist[t] = excl[t];  // reuse as local placement cursor
  __syncthreads();
#pragma unroll
  for (int i = 0; i < 16; ++i) {
    if (c[i] >= 0) {
      int b = c[i] >> 9;
      int p = atomicAdd(&hist[b], 1);
      stg[p] = make_int2(s[i], c[i]);
      lb[p] = (unsigned char)b;
    }
  }
  __syncthreads();
  int cntE = min(TILE, E - base);
#pragma unroll
  for (int i = 0; i < 16; ++i) {
    int p = i * 256 + t;
    if (p < cntE) {
      int b = lb[p];
      barr[gb[b] + (p - excl[b])] = stg[p];
    }
  }
}

// ---------------- bucket-level exclusive prefix (nbuck <= 256), 1 block ------
__global__ void k_bscan(const int* __restrict__ bcur, int* __restrict__ bstart,
                        int nbuck, int* __restrict__ rowptr, int N, int E) {
  __shared__ int s[256];
  int t = threadIdx.x;
  int v = (t < nbuck) ? (bcur[t] - t * BCAP) : 0;
  s[t] = v;
  __syncthreads();
  for (int off = 1; off < 256; off <<= 1) {
    int tv = (t >= off) ? s[t - off] : 0;
    __syncthreads();
    s[t] += tv;
    __syncthreads();
  }
  if (t < nbuck) bstart[t] = s[t] - v;
  if (t == 0) rowptr[N] = E;
}

// ---------------- pass B: bucket -> CSR; also emits rowptr & dinv ------------
__global__ __launch_bounds__(512) void k_finalize(const int* __restrict__ bcur,
                                                  const int* __restrict__ bstart,
                                                  const int2* __restrict__ barr,
                                                  int* __restrict__ rowptr,
                                                  float* __restrict__ dinv,
                                                  int* __restrict__ ed4, int N) {
  __shared__ int cnt[512];
  __shared__ int sbuf[512];
  __shared__ int cur[512];
  int b = blockIdx.x;
  int node0 = b << 9;
  int nn = min(512, N - node0);
  int t = threadIdx.x;
  cnt[t] = 0;
  __syncthreads();
  int m = bcur[b] - b * BCAP;  // edges in this bucket
  int src = b * BCAP;
  int bst = bstart[b];
  for (int i = t; i < m; i += 512) atomicAdd(&cnt[barr[src + i].y - node0], 1);
  __syncthreads();
  int v = cnt[t];
  sbuf[t] = v;
  __syncthreads();
  for (int off = 1; off < 512; off <<= 1) {
    int tv = (t >= off) ? sbuf[t - off] : 0;
    __syncthreads();
    sbuf[t] += tv;
    __syncthreads();
  }
  int excl = sbuf[t] - v;
  if (t < nn) {
    rowptr[node0 + t] = bst + excl;
    dinv[node0 + t] = rsqrtf((float)v + 1.0f);
  }
  cur[t] = bst + excl;
  __syncthreads();
  for (int i = t; i < m; i += 512) {
    int2 q = barr[src + i];
    int slot = atomicAdd(&cur[q.y - node0], 1);
    ed4[slot] = q.x;
  }
}

// ---------------- W pack: split fp32 W into bf16 hi/lo, MFMA B-frag layout ----
__global__ void k_prep_w(const float* __restrict__ W, short* __restrict__ Whp,
                         short* __restrict__ Wlp) {
  int i = blockIdx.x * 256 + threadIdx.x;  // 0..16383
  int j = i & 7;
  int lane = (i >> 3) & 63;
  int cg = (i >> 9) & 3;
  int kc = i >> 11;
  int k = kc * 32 + (lane >> 4) * 8 + j;
  int col = cg * 16 + (lane & 15);
  float w = W[k * 64 + col];
  unsigned u = __float_as_uint(w);
  unsigned hbits = u & 0xFFFF0000u;  // truncate: residual captured exactly by lo
  Whp[i] = (short)(hbits >> 16);
  Wlp[i] = (short)f2bf(w - __uint_as_float(hbits));
}

// ---------------- h = relu(x @ W1 + b1), split-precision bf16 MFMA -----------
// Locality-preserving 2-tile wave pipeline: sequential 128-row blocks (782,
// in order, so L3 keeps ~half of x resident across dispatches — round-8 lesson),
// 4 waves/block, each wave owns TWO consecutive 16-row tiles. Both tiles' x
// loads are issued up front (32 loads in flight/wave); epilogue goes through a
// PER-WAVE private LDS slice (no __syncthreads after W staging, so tile B's
// loads stay in flight across tile A's compute via per-wave counted vmcnt).
// Wh staged in LDS (32 KB); Wl fragments read from L2/L3-hot global.
#define GEMM_COMPUTE_EPI(XA, XB, T)                                              \
  {                                                                              \
    f32x4 acc[4];                                                                \
    _Pragma("unroll") for (int cg = 0; cg < 4; ++cg) acc[cg] =                   \
        (f32x4){0.f, 0.f, 0.f, 0.f};                                             \
    _Pragma("unroll") for (int kc = 0; kc < 8; ++kc) {                           \
      float f[8] = {XA[kc].x, XA[kc].y, XA[kc].z, XA[kc].w,                      \
                    XB[kc].x, XB[kc].y, XB[kc].z, XB[kc].w};                     \
      bf16x8 xh, xl;                                                             \
      _Pragma("unroll") for (int j = 0; j < 8; ++j) {                            \
        unsigned u_ = __float_as_uint(f[j]);                                     \
        unsigned hb_ = u_ & 0xFFFF0000u;                                         \
        xh[j] = (short)(hb_ >> 16);                                              \
        xl[j] = (short)f2bf(f[j] - __uint_as_float(hb_));                        \
      }                                                                          \
      _Pragma("unroll") for (int cg = 0; cg < 4; ++cg) {                         \
        const bf16x8 wh = *(const bf16x8*)&WhS[((kc * 4 + cg) * 64 + lane) * 8]; \
        const bf16x8 wl = *(const bf16x8*)&Wlp[((kc * 4 + cg) * 64 + lane) * 8]; \
        acc[cg] = __builtin_amdgcn_mfma_f32_16x16x32_bf16(xh, wh, acc[cg], 0, 0, 0); \
        acc[cg] = __builtin_amdgcn_mfma_f32_16x16x32_bf16(xl, wh, acc[cg], 0, 0, 0); \
        acc[cg] = __builtin_amdgcn_mfma_f32_16x16x32_bf16(xh, wl, acc[cg], 0, 0, 0); \
      }                                                                          \
    }                                                                            \
    _Pragma("unroll") for (int cg = 0; cg < 4; ++cg) {                           \
      _Pragma("unroll") for (int r = 0; r < 4; ++r) {                            \
        Cw[(q * 4 + r) * 68 + cg * 16 + rr] = fmaxf(acc[cg][r] + bias[cg], 0.f); \
      }                                                                          \
    }                                                                            \
    {                                                                            \
      int lr = lane >> 2;                                                        \
      int cq = lane & 3;                                                         \
      long grow = (long)(T)*16 + lr;                                             \
      if (grow < N) {                                                            \
        union F4U { f32x4 v; float f[4]; };                                      \
        const float* cp = &Cw[lr * 68 + cq * 16];                                \
        F4U w0, w1, w2, w3;                                                      \
        w0.v = *(const f32x4*)cp;                                                \
        w1.v = *(const f32x4*)(cp + 4);                                          \
        w2.v = *(const f32x4*)(cp + 8);                                          \
        w3.v = *(const f32x4*)(cp + 12);                                         \
        size_t ob = (size_t)grow * 64 + cq * 16;                                 \
        float* hp = h + ob;                                                      \
        *(f32x4*)hp = w0.v;                                                      \
        *(f32x4*)(hp + 4) = w1.v;                                                \
        *(f32x4*)(hp + 8) = w2.v;                                                \
        *(f32x4*)(hp + 12) = w3.v;                                               \
        float dv = dinv[grow];                                                   \
        uint4 ub, ub2, uz, uz2;                                                  \
        ub.x = (unsigned)f2bf(w0.f[0]) | ((unsigned)f2bf(w0.f[1]) << 16);        \
        ub.y = (unsigned)f2bf(w0.f[2]) | ((unsigned)f2bf(w0.f[3]) << 16);        \
        ub.z = (unsigned)f2bf(w1.f[0]) | ((unsigned)f2bf(w1.f[1]) << 16);        \
        ub.w = (unsigned)f2bf(w1.f[2]) | ((unsigned)f2bf(w1.f[3]) << 16);        \
        ub2.x = (unsigned)f2bf(w2.f[0]) | ((unsigned)f2bf(w2.f[1]) << 16);       \
        ub2.y = (unsigned)f2bf(w2.f[2]) | ((unsigned)f2bf(w2.f[3]) << 16);       \
        ub2.z = (unsigned)f2bf(w3.f[0]) | ((unsigned)f2bf(w3.f[1]) << 16);       \
        ub2.w = (unsigned)f2bf(w3.f[2]) | ((unsigned)f2bf(w3.f[3]) << 16);       \
        uz.x = (unsigned)f2bf(dv * w0.f[0]) | ((unsigned)f2bf(dv * w0.f[1]) << 16); \
        uz.y = (unsigned)f2bf(dv * w0.f[2]) | ((unsigned)f2bf(dv * w0.f[3]) << 16); \
        uz.z = (unsigned)f2bf(dv * w1.f[0]) | ((unsigned)f2bf(dv * w1.f[1]) << 16); \
        uz.w = (unsigned)f2bf(dv * w1.f[2]) | ((unsigned)f2bf(dv * w1.f[3]) << 16); \
        uz2.x = (unsigned)f2bf(dv * w2.f[0]) | ((unsigned)f2bf(dv * w2.f[1]) << 16); \
        uz2.y = (unsigned)f2bf(dv * w2.f[2]) | ((unsigned)f2bf(dv * w2.f[3]) << 16); \
        uz2.z = (unsigned)f2bf(dv * w3.f[0]) | ((unsigned)f2bf(dv * w3.f[1]) << 16); \
        uz2.w = (unsigned)f2bf(dv * w3.f[2]) | ((unsigned)f2bf(dv * w3.f[3]) << 16); \
        *(uint4*)(hb + ob) = ub;                                                 \
        *(uint4*)(hb + ob + 8) = ub2;                                            \
        *(uint4*)(zs0 + ob) = uz;                                                \
        *(uint4*)(zs0 + ob + 8) = uz2;                                           \
      }                                                                          \
    }                                                                            \
  }

#define GEMM_PREFETCH(XA, XB, T)                                                 \
  {                                                                              \
    long arow_ = (long)(T)*16 + rr;                                              \
    if (arow_ > N - 1) arow_ = N - 1;                                            \
    const float* xr_ = x + arow_ * 256 + q * 8;                                  \
    _Pragma("unroll") for (int kc = 0; kc < 8; ++kc) {                           \
      XA[kc] = *(const f32x4*)(xr_ + kc * 32);                                   \
      XB[kc] = *(const f32x4*)(xr_ + kc * 32 + 4);                               \
    }                                                                            \
  }

__global__ __launch_bounds__(256) void k_gemm_mfma(const float* __restrict__ x,
                                                   const short* __restrict__ Whp,
                                                   const short* __restrict__ Wlp,
                                                   const float* __restrict__ b,
                                                   const float* __restrict__ dinv,
                                                   float* __restrict__ h,
                                                   bf16_t* __restrict__ hb,
                                                   bf16_t* __restrict__ zs0, int N) {
  __shared__ __align__(16) char smem[50176];  // 32KB Wh + 4 x (16x68 f32) slices
  short* WhS = (short*)smem;
  int tid = threadIdx.x;
  for (int i = tid; i < 2048; i += 256) {
    ((int4*)WhS)[i] = ((const int4*)Whp)[i];
  }
  __syncthreads();
  int wid = tid >> 6;
  int lane = tid & 63;
  int rr = lane & 15;
  int q = lane >> 4;
  float* Cw = (float*)(smem + 32768) + wid * 1088;  // per-wave private slice

  float bias[4];
#pragma unroll
  for (int cg = 0; cg < 4; ++cg) bias[cg] = b[cg * 16 + rr];

  int ntiles = (N + 15) >> 4;
  int tA = blockIdx.x * 8 + wid;      // wave's first 16-row tile
  int tB = tA + 4;                    // wave's second tile (same block, +64 rows)
  bool hasA = tA < ntiles;
  bool hasB = tB < ntiles;

  f32x4 xaA[8], xbA[8], xaB[8], xbB[8];
  if (hasA) GEMM_PREFETCH(xaA, xbA, tA);
  if (hasB) GEMM_PREFETCH(xaB, xbB, tB);
  if (hasA) GEMM_COMPUTE_EPI(xaA, xbA, tA);
  if (hasB) GEMM_COMPUTE_EPI(xaB, xbB, tB);
}

// ---------------- propagation: 8 lanes/node, bf16x8 gathers ------------------
template <int LAST>
__global__ __launch_bounds__(256) void k_prop(const int* __restrict__ rowptr,
                                              const int* __restrict__ ed4,
                                              const float* __restrict__ dinv,
                                              const bf16_t* __restrict__ zin,
                                              const bf16_t* __restrict__ hbi,
                                              const float* __restrict__ hf,
                                              void* __restrict__ zout_, int N) {
  int tid = threadIdx.x;
  int lane = tid & 63;
  int u = lane & 7;       // channel octet: channels u*8 .. u*8+7
  int g = lane >> 3;      // node sub-index within wave (0..7)
  int gbase = lane & 56;  // first lane of this group
  int node = blockIdx.x * 32 + (tid >> 6) * 8 + g;
  bool live = node < N;
  if (!live) node = N - 1;  // clamp; stores guarded
  int beg = rowptr[node];
  int m = rowptr[node + 1] - beg;
  float dvc = dinv[node];
  size_t base = (size_t)node * 64 + u * 8;

  union V { bf16x8 v; unsigned d[4]; };
  V zs;
  zs.v = *(const bf16x8*)(zin + base);  // self term (already dinv-scaled)
  float a0 = __uint_as_float(zs.d[0] << 16);
  float a1 = __uint_as_float(zs.d[0] & 0xFFFF0000u);
  float a2 = __uint_as_float(zs.d[1] << 16);
  float a3 = __uint_as_float(zs.d[1] & 0xFFFF0000u);
  float a4 = __uint_as_float(zs.d[2] << 16);
  float a5 = __uint_as_float(zs.d[2] & 0xFFFF0000u);
  float a6 = __uint_as_float(zs.d[3] << 16);
  float a7 = __uint_as_float(zs.d[3] & 0xFFFF0000u);

  int full = m & ~7;
  for (int off = 0; off < full; off += 8) {
    int ev = ed4[beg + off + u];
#pragma unroll
    for (int j = 0; j < 8; ++j) {
      int src = __shfl(ev, gbase + j, 64);
      V z;
      z.v = *(const bf16x8*)(zin + (size_t)src * 64 + u * 8);
      a0 += __uint_as_float(z.d[0] << 16);
      a1 += __uint_as_float(z.d[0] & 0xFFFF0000u);
      a2 += __uint_as_float(z.d[1] << 16);
      a3 += __uint_as_float(z.d[1] & 0xFFFF0000u);
      a4 += __uint_as_float(z.d[2] << 16);
      a5 += __uint_as_float(z.d[2] & 0xFFFF0000u);
      a6 += __uint_as_float(z.d[3] << 16);
      a7 += __uint_as_float(z.d[3] & 0xFFFF0000u);
    }
  }
  int rem = m - full;
  if (rem > 0) {
    int ev = (u < rem) ? ed4[beg + full + u] : 0;
    for (int j = 0; j < rem; ++j) {
      int src = __shfl(ev, gbase + j, 64);
      V z;
      z.v = *(const bf16x8*)(zin + (size_t)src * 64 + u * 8);
      a0 += __uint_as_float(z.d[0] << 16);
      a1 += __uint_as_float(z.d[0] & 0xFFFF0000u);
      a2 += __uint_as_float(z.d[1] << 16);
      a3 += __uint_as_float(z.d[1] & 0xFFFF0000u);
      a4 += __uint_as_float(z.d[2] << 16);
      a5 += __uint_as_float(z.d[2] & 0xFFFF0000u);
      a6 += __uint_as_float(z.d[3] << 16);
      a7 += __uint_as_float(z.d[3] & 0xFFFF0000u);
    }
  }

  float sca = 0.9f * dvc;
  if (LAST) {
    const float* hp = hf + base;
    f32x4 h0 = *(const f32x4*)hp;
    f32x4 h1 = *(const f32x4*)(hp + 4);
    f32x4 r0, r1;
    r0.x = sca * a0 + 0.1f * h0.x;
    r0.y = sca * a1 + 0.1f * h0.y;
    r0.z = sca * a2 + 0.1f * h0.z;
    r0.w = sca * a3 + 0.1f * h0.w;
    r1.x = sca * a4 + 0.1f * h1.x;
    r1.y = sca * a5 + 0.1f * h1.y;
    r1.z = sca * a6 + 0.1f * h1.z;
    r1.w = sca * a7 + 0.1f * h1.w;
    if (live) {
      float* zp = (float*)zout_ + base;
      *(f32x4*)zp = r0;
      *(f32x4*)(zp + 4) = r1;
    }
  } else {
    V hv;
    hv.v = *(const bf16x8*)(hbi + base);
    float r0 = dvc * (sca * a0 + 0.1f * __uint_as_float(hv.d[0] << 16));
    float r1 = dvc * (sca * a1 + 0.1f * __uint_as_float(hv.d[0] & 0xFFFF0000u));
    float r2 = dvc * (sca * a2 + 0.1f * __uint_as_float(hv.d[1] << 16));
    float r3 = dvc * (sca * a3 + 0.1f * __uint_as_float(hv.d[1] & 0xFFFF0000u));
    float r4 = dvc * (sca * a4 + 0.1f * __uint_as_float(hv.d[2] << 16));
    float r5 = dvc * (sca * a5 + 0.1f * __uint_as_float(hv.d[2] & 0xFFFF0000u));
    float r6 = dvc * (sca * a6 + 0.1f * __uint_as_float(hv.d[3] << 16));
    float r7 = dvc * (sca * a7 + 0.1f * __uint_as_float(hv.d[3] & 0xFFFF0000u));
    uint4 o;
    o.x = (unsigned)f2bf(r0) | (((unsigned)f2bf(r1)) << 16);
    o.y = (unsigned)f2bf(r2) | (((unsigned)f2bf(r3)) << 16);
    o.z = (unsigned)f2bf(r4) | (((unsigned)f2bf(r5)) << 16);
    o.w = (unsigned)f2bf(r6) | (((unsigned)f2bf(r7)) << 16);
    if (live) *(uint4*)((bf16_t*)zout_ + base) = o;
  }
}

// ---------------- launch ----------------

extern "C" void kernel_launch(void* const* d_in, const int* in_sizes, int n_in,
                              void* d_out, int out_size, void* d_ws, size_t ws_size,
                              hipStream_t stream) {
  const float* x = (const float*)d_in[0];
  const int* ei = (const int*)d_in[1];  // int32 per harness contract
  const float* W1 = (const float*)d_in[2];
  const float* b1 = (const float*)d_in[3];
  float* zfinal = (float*)d_out;

  int OUT = in_sizes[3];        // 64
  int IN = in_sizes[2] / OUT;   // 256
  int N = in_sizes[0] / IN;     // 100000
  int E = in_sizes[1] / 2;      // 1600000

  char* ws = (char*)d_ws;
  size_t off = 0;
  auto alloc = [&](size_t bytes) -> char* {
    char* p = ws + off;
    off = (off + bytes + 255) & ~(size_t)255;
    return p;
  };
  int nbuck = (N + 511) >> 9;  // 196
  float* h = (float*)alloc((size_t)N * OUT * 4);       // 25.6 MB
  bf16_t* hb = (bf16_t*)alloc((size_t)N * OUT * 2);    // 12.8 MB
  bf16_t* zs0 = (bf16_t*)alloc((size_t)N * OUT * 2);   // 12.8 MB
  bf16_t* z0 = (bf16_t*)alloc((size_t)N * OUT * 2);    // 12.8 MB
  bf16_t* z1 = (bf16_t*)alloc((size_t)N * OUT * 2);    // 12.8 MB
  int2* barr = (int2*)alloc((size_t)nbuck * BCAP * 8); // 25.7 MB
  int* ed4 = (int*)alloc((size_t)E * 4 + 64);          // 6.4 MB
  short* Whp = (short*)alloc(16384 * 2);
  short* Wlp = (short*)alloc(16384 * 2);
  int* rowptr = (int*)alloc((size_t)(N + 1) * 4);
  float* dinv = (float*)alloc((size_t)N * 4);
  int* bcur = (int*)alloc(256 * 4);
  int* bstart = (int*)alloc(256 * 4);
  (void)ws_size;

  hipLaunchKernelGGL(k_initb, dim3(1), dim3(256), 0, stream, bcur, nbuck);
  hipLaunchKernelGGL(k_bucket, dim3((E + TILE - 1) / TILE), dim3(256), 0, stream, ei, E,
                     bcur, barr);
  hipLaunchKernelGGL(k_bscan, dim3(1), dim3(256), 0, stream, bcur, bstart, nbuck, rowptr,
                     N, E);
  hipLaunchKernelGGL(k_finalize, dim3(nbuck), dim3(512), 0, stream, bcur, bstart, barr,
                     rowptr, dinv, ed4, N);
  hipLaunchKernelGGL(k_prep_w, dim3(64), dim3(256), 0, stream, W1, Whp, Wlp);
  int ntiles = (N + 15) / 16;
  hipLaunchKernelGGL(k_gemm_mfma, dim3((ntiles + 7) / 8), dim3(256), 0, stream, x, Whp,
                     Wlp, b1, dinv, h, hb, zs0, N);

  dim3 pgrid((N + 31) / 32);  // 256 threads = 4 waves x 8 nodes = 32 nodes/block
  const bf16_t* zi = zs0;
  bf16_t* zb[2] = {z0, z1};
  for (int it = 0; it < KITER - 1; ++it) {
    bf16_t* zo = zb[it & 1];
    hipLaunchKernelGGL((k_prop<0>), pgrid, dim3(256), 0, stream, rowptr, ed4, dinv, zi,
                       hb, h, (void*)zo, N);
    zi = zo;
  }
  hipLaunchKernelGGL((k_prop<1>), pgrid, dim3(256), 0, stream, rowptr, ed4, dinv, zi, hb,
                     h, (void*)zfinal, N);
}

// Round 10
// 403.960 us; speedup vs baseline: 1.1398x; 1.0559x over previous
//
#include <hip/hip_runtime.h>

#define KITER 10
#define TILE 4096
#define BCAP 16384  // bucket staging capacity (expected 8192/bucket, +90 sigma)
typedef unsigned short bf16_t;
typedef __attribute__((ext_vector_type(4))) short bf16x4;
typedef __attribute__((ext_vector_type(8))) short bf16x8;
typedef __attribute__((ext_vector_type(4))) float f32x4;

__device__ __forceinline__ float bf2f(bf16_t u) {
  union { unsigned u; float f; } cv;
  cv.u = ((unsigned)u) << 16;
  return cv.f;
}
__device__ __forceinline__ bf16_t f2bf(float f) {
  unsigned u = __float_as_uint(f);
  unsigned r = (u + 0x7FFFu + ((u >> 16) & 1u)) >> 16;  // round-nearest-even
  return (bf16_t)r;
}

// ---------------- bucket cursor init: bcur[b] = b*BCAP ----------------
__global__ void k_initb(int* __restrict__ bcur, int nbuck) {
  int i = threadIdx.x;
  if (i < nbuck) bcur[i] = i * BCAP;
}

// ---------------- bucket sort pass A: tile -> per-bucket coalesced runs ------
__global__ __launch_bounds__(256) void k_bucket(const int* __restrict__ ei, int E,
                                                int* __restrict__ bcur,
                                                int2* __restrict__ barr) {
  __shared__ int hist[256];
  __shared__ int scn[256];
  __shared__ int excl[256];
  __shared__ int gb[256];
  __shared__ unsigned char lb[TILE];
  __shared__ int2 stg[TILE];
  int t = threadIdx.x;
  int base = blockIdx.x * TILE;
  hist[t] = 0;
  __syncthreads();
  int s[16], c[16];
#pragma unroll
  for (int i = 0; i < 16; ++i) {
    int e = base + i * 256 + t;
    if (e < E) {
      s[i] = ei[e];
      c[i] = ei[E + e];
      atomicAdd(&hist[c[i] >> 9], 1);
    } else {
      c[i] = -1;
    }
  }
  __syncthreads();
  int h = hist[t];
  scn[t] = h;
  __syncthreads();
  for (int off = 1; off < 256; off <<= 1) {
    int v = (t >= off) ? scn[t - off] : 0;
    __syncthreads();
    scn[t] += v;
    __syncthreads();
  }
  excl[t] = scn[t] - h;
  gb[t] = (h > 0) ? atomicAdd(&bcur[t], h) : 0;
  __syncthreads();
  hist[t] = excl[t];  // reuse as local placement cursor
  __syncthreads();
#pragma unroll
  for (int i = 0; i < 16; ++i) {
    if (c[i] >= 0) {
      int b = c[i] >> 9;
      int p = atomicAdd(&hist[b], 1);
      stg[p] = make_int2(s[i], c[i]);
      lb[p] = (unsigned char)b;
    }
  }
  __syncthreads();
  int cntE = min(TILE, E - base);
#pragma unroll
  for (int i = 0; i < 16; ++i) {
    int p = i * 256 + t;
    if (p < cntE) {
      int b = lb[p];
      barr[gb[b] + (p - excl[b])] = stg[p];
    }
  }
}

// ---------------- bucket-level exclusive prefix (nbuck <= 256), 1 block ------
__global__ void k_bscan(const int* __restrict__ bcur, int* __restrict__ bstart,
                        int nbuck, int* __restrict__ rowptr, int N, int E) {
  __shared__ int s[256];
  int t = threadIdx.x;
  int v = (t < nbuck) ? (bcur[t] - t * BCAP) : 0;
  s[t] = v;
  __syncthreads();
  for (int off = 1; off < 256; off <<= 1) {
    int tv = (t >= off) ? s[t - off] : 0;
    __syncthreads();
    s[t] += tv;
    __syncthreads();
  }
  if (t < nbuck) bstart[t] = s[t] - v;
  if (t == 0) rowptr[N] = E;
}

// ---------------- pass B: bucket -> CSR; also emits rowptr & dinv ------------
__global__ __launch_bounds__(512) void k_finalize(const int* __restrict__ bcur,
                                                  const int* __restrict__ bstart,
                                                  const int2* __restrict__ barr,
                                                  int* __restrict__ rowptr,
                                                  float* __restrict__ dinv,
                                                  int* __restrict__ ed4, int N) {
  __shared__ int cnt[512];
  __shared__ int sbuf[512];
  __shared__ int cur[512];
  int b = blockIdx.x;
  int node0 = b << 9;
  int nn = min(512, N - node0);
  int t = threadIdx.x;
  cnt[t] = 0;
  __syncthreads();
  int m = bcur[b] - b * BCAP;  // edges in this bucket
  int src = b * BCAP;
  int bst = bstart[b];
  for (int i = t; i < m; i += 512) atomicAdd(&cnt[barr[src + i].y - node0], 1);
  __syncthreads();
  int v = cnt[t];
  sbuf[t] = v;
  __syncthreads();
  for (int off = 1; off < 512; off <<= 1) {
    int tv = (t >= off) ? sbuf[t - off] : 0;
    __syncthreads();
    sbuf[t] += tv;
    __syncthreads();
  }
  int excl = sbuf[t] - v;
  if (t < nn) {
    rowptr[node0 + t] = bst + excl;
    dinv[node0 + t] = rsqrtf((float)v + 1.0f);
  }
  cur[t] = bst + excl;
  __syncthreads();
  for (int i = t; i < m; i += 512) {
    int2 q = barr[src + i];
    int slot = atomicAdd(&cur[q.y - node0], 1);
    ed4[slot] = q.x;
  }
}

// ---------------- W pack: split fp32 W into bf16 hi/lo, MFMA B-frag layout ----
__global__ void k_prep_w(const float* __restrict__ W, short* __restrict__ Whp,
                         short* __restrict__ Wlp) {
  int i = blockIdx.x * 256 + threadIdx.x;  // 0..16383
  int j = i & 7;
  int lane = (i >> 3) & 63;
  int cg = (i >> 9) & 3;
  int kc = i >> 11;
  int k = kc * 32 + (lane >> 4) * 8 + j;
  int col = cg * 16 + (lane & 15);
  float w = W[k * 64 + col];
  unsigned u = __float_as_uint(w);
  unsigned hbits = u & 0xFFFF0000u;  // truncate: residual captured exactly by lo
  Whp[i] = (short)(hbits >> 16);
  Wlp[i] = (short)f2bf(w - __uint_as_float(hbits));
}

// ---------------- h = relu(x @ W1 + b1), split-precision bf16 MFMA -----------
// REVERT to the measured-best round-5 configuration (64.6 us): 512 thr = 8
// waves, W hi/lo staged in LDS (64 KB), full x reg prefetch, bias+relu in-reg,
// C tile staged through LDS (reusing the W buffer post-compute, stride 68),
// then fully coalesced full-line writeout (thread t -> row t>>2, quarter t&3).
// Pipelining variants (R8 grid-stride, R9 2-tile) both regressed via locality /
// occupancy side effects — this structure is the empirical optimum of 6 tried.
__global__ __launch_bounds__(512) void k_gemm_mfma(const float* __restrict__ x,
                                                   const short* __restrict__ Whp,
                                                   const short* __restrict__ Wlp,
                                                   const float* __restrict__ b,
                                                   const float* __restrict__ dinv,
                                                   float* __restrict__ h,
                                                   bf16_t* __restrict__ hb,
                                                   bf16_t* __restrict__ zs0, int N) {
  __shared__ __align__(16) char smem[65536];
  short* WhS = (short*)smem;             // 32 KB
  short* WlS = (short*)(smem + 32768);   // 32 KB
  float* Cst = (float*)smem;             // reused post-compute: 128 x 68 floats
  int tid = threadIdx.x;
  for (int i = tid; i < 2048; i += 512) {
    ((int4*)WhS)[i] = ((const int4*)Whp)[i];
    ((int4*)WlS)[i] = ((const int4*)Wlp)[i];
  }
  __syncthreads();
  int wid = tid >> 6;
  int lane = tid & 63;
  int rr = lane & 15;
  int q = lane >> 4;
  long row0 = (long)blockIdx.x * 128 + wid * 16;
  long arow = row0 + rr;
  if (arow > N - 1) arow = N - 1;  // clamp (stores guarded)
  const float* xr = x + arow * 256 + q * 8;

  // prefetch whole row slice: 8 kchunks x 8 floats
  f32x4 xa[8], xb[8];
#pragma unroll
  for (int kc = 0; kc < 8; ++kc) {
    xa[kc] = *(const f32x4*)(xr + kc * 32);
    xb[kc] = *(const f32x4*)(xr + kc * 32 + 4);
  }

  f32x4 acc[4];
#pragma unroll
  for (int cg = 0; cg < 4; ++cg) acc[cg] = (f32x4){0.f, 0.f, 0.f, 0.f};

#pragma unroll
  for (int kc = 0; kc < 8; ++kc) {
    float f[8] = {xa[kc].x, xa[kc].y, xa[kc].z, xa[kc].w,
                  xb[kc].x, xb[kc].y, xb[kc].z, xb[kc].w};
    bf16x8 xh, xl;
#pragma unroll
    for (int j = 0; j < 8; ++j) {
      unsigned u = __float_as_uint(f[j]);
      unsigned hbits = u & 0xFFFF0000u;
      xh[j] = (short)(hbits >> 16);
      xl[j] = (short)f2bf(f[j] - __uint_as_float(hbits));
    }
#pragma unroll
    for (int cg = 0; cg < 4; ++cg) {
      const bf16x8 wh = *(const bf16x8*)&WhS[((kc * 4 + cg) * 64 + lane) * 8];
      const bf16x8 wl = *(const bf16x8*)&WlS[((kc * 4 + cg) * 64 + lane) * 8];
      acc[cg] = __builtin_amdgcn_mfma_f32_16x16x32_bf16(xh, wh, acc[cg], 0, 0, 0);
      acc[cg] = __builtin_amdgcn_mfma_f32_16x16x32_bf16(xl, wh, acc[cg], 0, 0, 0);
      acc[cg] = __builtin_amdgcn_mfma_f32_16x16x32_bf16(xh, wl, acc[cg], 0, 0, 0);
    }
  }

  // -------- epilogue: bias+relu in-reg, stage C tile to LDS (W is dead) -----
  __syncthreads();  // all waves finished reading WhS/WlS
#pragma unroll
  for (int cg = 0; cg < 4; ++cg) {
    float bias = b[cg * 16 + rr];
#pragma unroll
    for (int r = 0; r < 4; ++r) {
      float v = fmaxf(acc[cg][r] + bias, 0.f);
      Cst[(wid * 16 + q * 4 + r) * 68 + cg * 16 + rr] = v;
    }
  }
  __syncthreads();

  // -------- coalesced writeout: thread t -> row t>>2, col quarter t&3 -------
  int lrow = tid >> 2;
  int cq = tid & 3;
  long grow = (long)blockIdx.x * 128 + lrow;
  if (grow < N) {
    union F4U { f32x4 v; float f[4]; };
    const float* cp = &Cst[lrow * 68 + cq * 16];
    F4U w0, w1, w2, w3;
    w0.v = *(const f32x4*)cp;
    w1.v = *(const f32x4*)(cp + 4);
    w2.v = *(const f32x4*)(cp + 8);
    w3.v = *(const f32x4*)(cp + 12);
    size_t ob = (size_t)grow * 64 + cq * 16;
    float* hp = h + ob;
    *(f32x4*)hp = w0.v;
    *(f32x4*)(hp + 4) = w1.v;
    *(f32x4*)(hp + 8) = w2.v;
    *(f32x4*)(hp + 12) = w3.v;
    float dv = dinv[grow];
    uint4 ub, ub2, uz, uz2;
    ub.x = (unsigned)f2bf(w0.f[0]) | ((unsigned)f2bf(w0.f[1]) << 16);
    ub.y = (unsigned)f2bf(w0.f[2]) | ((unsigned)f2bf(w0.f[3]) << 16);
    ub.z = (unsigned)f2bf(w1.f[0]) | ((unsigned)f2bf(w1.f[1]) << 16);
    ub.w = (unsigned)f2bf(w1.f[2]) | ((unsigned)f2bf(w1.f[3]) << 16);
    ub2.x = (unsigned)f2bf(w2.f[0]) | ((unsigned)f2bf(w2.f[1]) << 16);
    ub2.y = (unsigned)f2bf(w2.f[2]) | ((unsigned)f2bf(w2.f[3]) << 16);
    ub2.z = (unsigned)f2bf(w3.f[0]) | ((unsigned)f2bf(w3.f[1]) << 16);
    ub2.w = (unsigned)f2bf(w3.f[2]) | ((unsigned)f2bf(w3.f[3]) << 16);
    uz.x = (unsigned)f2bf(dv * w0.f[0]) | ((unsigned)f2bf(dv * w0.f[1]) << 16);
    uz.y = (unsigned)f2bf(dv * w0.f[2]) | ((unsigned)f2bf(dv * w0.f[3]) << 16);
    uz.z = (unsigned)f2bf(dv * w1.f[0]) | ((unsigned)f2bf(dv * w1.f[1]) << 16);
    uz.w = (unsigned)f2bf(dv * w1.f[2]) | ((unsigned)f2bf(dv * w1.f[3]) << 16);
    uz2.x = (unsigned)f2bf(dv * w2.f[0]) | ((unsigned)f2bf(dv * w2.f[1]) << 16);
    uz2.y = (unsigned)f2bf(dv * w2.f[2]) | ((unsigned)f2bf(dv * w2.f[3]) << 16);
    uz2.z = (unsigned)f2bf(dv * w3.f[0]) | ((unsigned)f2bf(dv * w3.f[1]) << 16);
    uz2.w = (unsigned)f2bf(dv * w3.f[2]) | ((unsigned)f2bf(dv * w3.f[3]) << 16);
    *(uint4*)(hb + ob) = ub;
    *(uint4*)(hb + ob + 8) = ub2;
    *(uint4*)(zs0 + ob) = uz;
    *(uint4*)(zs0 + ob + 8) = uz2;
  }
}

// ---------------- propagation: 8 lanes/node, bf16x8 gathers ------------------
// NEW this round: ed4 index prefetch — the next chunk's edge-index load is
// issued BEFORE the current chunk's accumulate VALU, hiding its ~300 cy L2
// latency under ~270 cy of VALU (breaks the serial ed->shfl->gather chain).
// +1 VGPR, no sync, occupancy-neutral. Hypothesis test: win => prop is
// serialization-bound (keep pipelining); null => divergent-line (TA) bound.
template <int LAST>
__global__ __launch_bounds__(256) void k_prop(const int* __restrict__ rowptr,
                                              const int* __restrict__ ed4,
                                              const float* __restrict__ dinv,
                                              const bf16_t* __restrict__ zin,
                                              const bf16_t* __restrict__ hbi,
                                              const float* __restrict__ hf,
                                              void* __restrict__ zout_, int N) {
  int tid = threadIdx.x;
  int lane = tid & 63;
  int u = lane & 7;       // channel octet: channels u*8 .. u*8+7
  int g = lane >> 3;      // node sub-index within wave (0..7)
  int gbase = lane & 56;  // first lane of this group
  int node = blockIdx.x * 32 + (tid >> 6) * 8 + g;
  bool live = node < N;
  if (!live) node = N - 1;  // clamp; stores guarded
  int beg = rowptr[node];
  int m = rowptr[node + 1] - beg;
  float dvc = dinv[node];
  size_t base = (size_t)node * 64 + u * 8;

  union V { bf16x8 v; unsigned d[4]; };
  V zs;
  zs.v = *(const bf16x8*)(zin + base);  // self term (already dinv-scaled)
  float a0 = __uint_as_float(zs.d[0] << 16);
  float a1 = __uint_as_float(zs.d[0] & 0xFFFF0000u);
  float a2 = __uint_as_float(zs.d[1] << 16);
  float a3 = __uint_as_float(zs.d[1] & 0xFFFF0000u);
  float a4 = __uint_as_float(zs.d[2] << 16);
  float a5 = __uint_as_float(zs.d[2] & 0xFFFF0000u);
  float a6 = __uint_as_float(zs.d[3] << 16);
  float a7 = __uint_as_float(zs.d[3] & 0xFFFF0000u);

  int full = m & ~7;
  int ev = (full > 0) ? ed4[beg + u] : 0;
  for (int off = 0; off < full; off += 8) {
    int nxt = off + 8;
    int evn = (nxt < full) ? ed4[beg + nxt + u] : 0;  // prefetch next chunk
    V z0, z1, z2, z3, z4, z5, z6, z7;
    {
      int s0 = __shfl(ev, gbase + 0, 64);
      int s1 = __shfl(ev, gbase + 1, 64);
      int s2 = __shfl(ev, gbase + 2, 64);
      int s3 = __shfl(ev, gbase + 3, 64);
      int s4 = __shfl(ev, gbase + 4, 64);
      int s5 = __shfl(ev, gbase + 5, 64);
      int s6 = __shfl(ev, gbase + 6, 64);
      int s7 = __shfl(ev, gbase + 7, 64);
      z0.v = *(const bf16x8*)(zin + (size_t)s0 * 64 + u * 8);
      z1.v = *(const bf16x8*)(zin + (size_t)s1 * 64 + u * 8);
      z2.v = *(const bf16x8*)(zin + (size_t)s2 * 64 + u * 8);
      z3.v = *(const bf16x8*)(zin + (size_t)s3 * 64 + u * 8);
      z4.v = *(const bf16x8*)(zin + (size_t)s4 * 64 + u * 8);
      z5.v = *(const bf16x8*)(zin + (size_t)s5 * 64 + u * 8);
      z6.v = *(const bf16x8*)(zin + (size_t)s6 * 64 + u * 8);
      z7.v = *(const bf16x8*)(zin + (size_t)s7 * 64 + u * 8);
    }
#pragma unroll
    for (int j = 0; j < 8; ++j) {
      V* zp;
      switch (j) {
        case 0: zp = &z0; break;
        case 1: zp = &z1; break;
        case 2: zp = &z2; break;
        case 3: zp = &z3; break;
        case 4: zp = &z4; break;
        case 5: zp = &z5; break;
        case 6: zp = &z6; break;
        default: zp = &z7; break;
      }
      a0 += __uint_as_float(zp->d[0] << 16);
      a1 += __uint_as_float(zp->d[0] & 0xFFFF0000u);
      a2 += __uint_as_float(zp->d[1] << 16);
      a3 += __uint_as_float(zp->d[1] & 0xFFFF0000u);
      a4 += __uint_as_float(zp->d[2] << 16);
      a5 += __uint_as_float(zp->d[2] & 0xFFFF0000u);
      a6 += __uint_as_float(zp->d[3] << 16);
      a7 += __uint_as_float(zp->d[3] & 0xFFFF0000u);
    }
    ev = evn;
  }
  int rem = m - full;
  if (rem > 0) {
    int evr = (u < rem) ? ed4[beg + full + u] : 0;
    for (int j = 0; j < rem; ++j) {
      int src = __shfl(evr, gbase + j, 64);
      V z;
      z.v = *(const bf16x8*)(zin + (size_t)src * 64 + u * 8);
      a0 += __uint_as_float(z.d[0] << 16);
      a1 += __uint_as_float(z.d[0] & 0xFFFF0000u);
      a2 += __uint_as_float(z.d[1] << 16);
      a3 += __uint_as_float(z.d[1] & 0xFFFF0000u);
      a4 += __uint_as_float(z.d[2] << 16);
      a5 += __uint_as_float(z.d[2] & 0xFFFF0000u);
      a6 += __uint_as_float(z.d[3] << 16);
      a7 += __uint_as_float(z.d[3] & 0xFFFF0000u);
    }
  }

  float sca = 0.9f * dvc;
  if (LAST) {
    const float* hp = hf + base;
    f32x4 h0 = *(const f32x4*)hp;
    f32x4 h1 = *(const f32x4*)(hp + 4);
    f32x4 r0, r1;
    r0.x = sca * a0 + 0.1f * h0.x;
    r0.y = sca * a1 + 0.1f * h0.y;
    r0.z = sca * a2 + 0.1f * h0.z;
    r0.w = sca * a3 + 0.1f * h0.w;
    r1.x = sca * a4 + 0.1f * h1.x;
    r1.y = sca * a5 + 0.1f * h1.y;
    r1.z = sca * a6 + 0.1f * h1.z;
    r1.w = sca * a7 + 0.1f * h1.w;
    if (live) {
      float* zp = (float*)zout_ + base;
      *(f32x4*)zp = r0;
      *(f32x4*)(zp + 4) = r1;
    }
  } else {
    V hv;
    hv.v = *(const bf16x8*)(hbi + base);
    float r0 = dvc * (sca * a0 + 0.1f * __uint_as_float(hv.d[0] << 16));
    float r1 = dvc * (sca * a1 + 0.1f * __uint_as_float(hv.d[0] & 0xFFFF0000u));
    float r2 = dvc * (sca * a2 + 0.1f * __uint_as_float(hv.d[1] << 16));
    float r3 = dvc * (sca * a3 + 0.1f * __uint_as_float(hv.d[1] & 0xFFFF0000u));
    float r4 = dvc * (sca * a4 + 0.1f * __uint_as_float(hv.d[2] << 16));
    float r5 = dvc * (sca * a5 + 0.1f * __uint_as_float(hv.d[2] & 0xFFFF0000u));
    float r6 = dvc * (sca * a6 + 0.1f * __uint_as_float(hv.d[3] << 16));
    float r7 = dvc * (sca * a7 + 0.1f * __uint_as_float(hv.d[3] & 0xFFFF0000u));
    uint4 o;
    o.x = (unsigned)f2bf(r0) | (((unsigned)f2bf(r1)) << 16);
    o.y = (unsigned)f2bf(r2) | (((unsigned)f2bf(r3)) << 16);
    o.z = (unsigned)f2bf(r4) | (((unsigned)f2bf(r5)) << 16);
    o.w = (unsigned)f2bf(r6) | (((unsigned)f2bf(r7)) << 16);
    if (live) *(uint4*)((bf16_t*)zout_ + base) = o;
  }
}

// ---------------- launch ----------------

extern "C" void kernel_launch(void* const* d_in, const int* in_sizes, int n_in,
                              void* d_out, int out_size, void* d_ws, size_t ws_size,
                              hipStream_t stream) {
  const float* x = (const float*)d_in[0];
  const int* ei = (const int*)d_in[1];  // int32 per harness contract
  const float* W1 = (const float*)d_in[2];
  const float* b1 = (const float*)d_in[3];
  float* zfinal = (float*)d_out;

  int OUT = in_sizes[3];        // 64
  int IN = in_sizes[2] / OUT;   // 256
  int N = in_sizes[0] / IN;     // 100000
  int E = in_sizes[1] / 2;      // 1600000

  char* ws = (char*)d_ws;
  size_t off = 0;
  auto alloc = [&](size_t bytes) -> char* {
    char* p = ws + off;
    off = (off + bytes + 255) & ~(size_t)255;
    return p;
  };
  int nbuck = (N + 511) >> 9;  // 196
  float* h = (float*)alloc((size_t)N * OUT * 4);       // 25.6 MB
  bf16_t* hb = (bf16_t*)alloc((size_t)N * OUT * 2);    // 12.8 MB
  bf16_t* zs0 = (bf16_t*)alloc((size_t)N * OUT * 2);   // 12.8 MB
  bf16_t* z0 = (bf16_t*)alloc((size_t)N * OUT * 2);    // 12.8 MB
  bf16_t* z1 = (bf16_t*)alloc((size_t)N * OUT * 2);    // 12.8 MB
  int2* barr = (int2*)alloc((size_t)nbuck * BCAP * 8); // 25.7 MB
  int* ed4 = (int*)alloc((size_t)E * 4 + 64);          // 6.4 MB
  short* Whp = (short*)alloc(16384 * 2);
  short* Wlp = (short*)alloc(16384 * 2);
  int* rowptr = (int*)alloc((size_t)(N + 1) * 4);
  float* dinv = (float*)alloc((size_t)N * 4);
  int* bcur = (int*)alloc(256 * 4);
  int* bstart = (int*)alloc(256 * 4);
  (void)ws_size;

  hipLaunchKernelGGL(k_initb, dim3(1), dim3(256), 0, stream, bcur, nbuck);
  hipLaunchKernelGGL(k_bucket, dim3((E + TILE - 1) / TILE), dim3(256), 0, stream, ei, E,
                     bcur, barr);
  hipLaunchKernelGGL(k_bscan, dim3(1), dim3(256), 0, stream, bcur, bstart, nbuck, rowptr,
                     N, E);
  hipLaunchKernelGGL(k_finalize, dim3(nbuck), dim3(512), 0, stream, bcur, bstart, barr,
                     rowptr, dinv, ed4, N);
  hipLaunchKernelGGL(k_prep_w, dim3(64), dim3(256), 0, stream, W1, Whp, Wlp);
  hipLaunchKernelGGL(k_gemm_mfma, dim3((N + 127) / 128), dim3(512), 0, stream, x, Whp,
                     Wlp, b1, dinv, h, hb, zs0, N);

  dim3 pgrid((N + 31) / 32);  // 256 threads = 4 waves x 8 nodes = 32 nodes/block
  const bf16_t* zi = zs0;
  bf16_t* zb[2] = {z0, z1};
  for (int it = 0; it < KITER - 1; ++it) {
    bf16_t* zo = zb[it & 1];
    hipLaunchKernelGGL((k_prop<0>), pgrid, dim3(256), 0, stream, rowptr, ed4, dinv, zi,
                       hb, h, (void*)zo, N);
    zi = zo;
  }
  hipLaunchKernelGGL((k_prop<1>), pgrid, dim3(256), 0, stream, rowptr, ed4, dinv, zi, hb,
                     h, (void*)zfinal, N);
}